// Round 13
// baseline (243.988 us; speedup 1.0000x reference)
//
#include <hip/hip_runtime.h>
#include <hip/hip_fp16.h>

// GCN: h1 = relu(Agg(x@W1)+b1); h2 = relu(Agg(h1@W2)+b2); out = mean(h2)@Wc+bc
// norm(r,c)=dinv[r]*dinv[c] factors: GEMM epilogue prescales rows by dinv[r],
// agg sums rows, scales by dinv[c] at the end.
// R1: agg MLP (88->57). R2-R4: scattered global atomics = hard ~16 G/s ceiling.
// R5: bucket+fusion (339). R6: interleave+fp16 (272). R7: zero-atomic build (254).
// R9: MFMA fp16 gemms. R10: rank-at-count parallel scatter (230).
// R11: deeper agg ILP — NEUTRAL => aggs are THROUGHPUT-bound (bytes/lines),
//      not latency-bound.
// R12: (a) gathered tensors in FP8 e4m3 (cvt_pk_fp8_f32 in gemm epilogue,
//      cvt_pk_f32_fp8 decode in aggs, fp32 accum): row 256B->128B, lines/row
//      4->2; (b) dispatches 9->7: wt folded into hist, pool+final merged via
//      last-block-done (ctr zeroed by colscan, threadfence release/acquire).

typedef _Float16 half8 __attribute__((ext_vector_type(8)));
typedef float f32x4 __attribute__((ext_vector_type(4)));
typedef float f32x2 __attribute__((ext_vector_type(2)));

constexpr int N = 50000;
constexpr int E = 800000;
constexpr int D = 128;
constexpr int DOUT = 40;
constexpr int CAP = 64;               // slots/node (Poisson(16) tail ~1e-18)
constexpr int HB = 128;               // histogram chunks
constexpr int EPB = E / HB;           // 6250 edges/chunk
constexpr int HWRD = 12500;           // 50000 bytes = 12500 words
constexpr int GM = (N + 127) / 128;   // 391 gemm blocks
constexpr int NW = N / 4;             // 12500 agg blocks
constexpr int T4 = E / 4;             // 200000 scatter threads
constexpr int GF = 3 * GM;            // 1173 = 782 scatter + 391 gemm

// ---------------- Phase A: chunk histograms + per-edge rank + W transpose ---
__global__ __launch_bounds__(1024) void k_hist(const int* __restrict__ col,
                                               unsigned char* __restrict__ hist,
                                               unsigned char* __restrict__ rank,
                                               const float* __restrict__ W1,
                                               const float* __restrict__ W2,
                                               __half* __restrict__ T1,
                                               __half* __restrict__ T2) {
    __shared__ unsigned int h[HWRD];
    int b = blockIdx.x, t = threadIdx.x;
    if (b >= HB) {                        // 32 spare blocks: Wt[n][k]=fp16(W[k][n])
        int o = (b - HB) * 1024 + t;      // 0..32767
        const float* W = (o < 16384) ? W1 : W2;
        __half* T = (o < 16384) ? T1 : T2;
        int oo = o & 16383;
        int n = oo >> 7, k = oo & 127;
        T[oo] = (__half)W[k * 128 + n];
        return;
    }
    for (int i = t; i < HWRD; i += 1024) h[i] = 0;
    __syncthreads();
    int e0 = b * EPB;
    for (int e = e0 + t; e < e0 + EPB; e += 1024) {
        int c = col[e];
        unsigned int old = atomicAdd(&h[c >> 2], 1u << ((c & 3) * 8));
        rank[e] = (unsigned char)((old >> ((c & 3) * 8)) & 0xff);
    }
    __syncthreads();
    unsigned int* out = (unsigned int*)(hist + (size_t)b * 50000);
    for (int i = t; i < HWRD; i += 1024) out[i] = h[i];
}

// ---------------- Phase B: per-node prefix over chunks; deg + dinv ---------
__global__ void k_colscan(unsigned char* __restrict__ hist, int* __restrict__ deg,
                          float* __restrict__ dinv, int* __restrict__ ctr) {
    int c = blockIdx.x * 256 + threadIdx.x;
    if (c >= N) return;
    if (c == 0) *ctr = 0;                 // init for k_tail (stream-ordered)
    int sum = 0;
#pragma unroll 4
    for (int b = 0; b < HB; ++b) {
        size_t idx = (size_t)b * 50000 + c;
        int v = hist[idx];
        hist[idx] = (unsigned char)sum;   // exclusive prefix (deg<=255)
        sum += v;
    }
    deg[c] = sum;
    dinv[c] = rsqrtf((float)(sum + 1));   // +1 self loop
}

// ---------------- fp8 helpers (OCP e4m3 on gfx950) ----------------
__device__ __forceinline__ unsigned char f8enc(float v) {
    return (unsigned char)(__builtin_amdgcn_cvt_pk_fp8_f32(v, v, 0, false) & 0xff);
}
__device__ __forceinline__ void add8f8(float* a, uint2 u) {
    f32x2 f0 = __builtin_amdgcn_cvt_pk_f32_fp8(u.x, false);
    f32x2 f1 = __builtin_amdgcn_cvt_pk_f32_fp8(u.x, true);
    f32x2 f2 = __builtin_amdgcn_cvt_pk_f32_fp8(u.y, false);
    f32x2 f3 = __builtin_amdgcn_cvt_pk_f32_fp8(u.y, true);
    a[0] += f0[0]; a[1] += f0[1]; a[2] += f1[0]; a[3] += f1[1];
    a[4] += f2[0]; a[5] += f2[1]; a[6] += f3[0]; a[7] += f3[1];
}

// ---------------- MFMA GEMM: out8[r] = fp8(dinv[r] * (A[r] @ W)) -----------
__device__ __forceinline__ half8 ldA(const float* rowp, int koff) {
    float4 u0 = *(const float4*)(rowp + koff);
    float4 u1 = *(const float4*)(rowp + koff + 4);
    half8 r;
    r[0] = (_Float16)u0.x; r[1] = (_Float16)u0.y;
    r[2] = (_Float16)u0.z; r[3] = (_Float16)u0.w;
    r[4] = (_Float16)u1.x; r[5] = (_Float16)u1.y;
    r[6] = (_Float16)u1.z; r[7] = (_Float16)u1.w;
    return r;
}
__device__ __forceinline__ half8 ldA(const __half* rowp, int koff) {
    return *(const half8*)(rowp + koff);
}

template <typename TA>
__device__ __forceinline__ void mfma_gemm(const TA* __restrict__ A,
                                          const __half* __restrict__ Wt,
                                          const float* __restrict__ dinv,
                                          unsigned char* __restrict__ out8,
                                          int row0, int tid) {
    int wave = tid >> 6, lane = tid & 63;
    int quad = lane >> 4, c16 = lane & 15;
    int m0 = row0 + wave * 32;
    int ra = m0 + c16;      if (ra >= N) ra = 0;   // OOB rows: dummy read row 0
    int rb = m0 + 16 + c16; if (rb >= N) rb = 0;
    const TA* pa = A + (size_t)ra * D;
    const TA* pb = A + (size_t)rb * D;

    f32x4 acc[2][8];
#pragma unroll
    for (int i = 0; i < 2; ++i)
#pragma unroll
        for (int j = 0; j < 8; ++j) acc[i][j] = (f32x4){0.f, 0.f, 0.f, 0.f};

#pragma unroll
    for (int kq = 0; kq < 4; ++kq) {
        int koff = kq * 32 + quad * 8;
        half8 a0 = ldA(pa, koff);
        half8 a1 = ldA(pb, koff);
#pragma unroll
        for (int nt = 0; nt < 8; ++nt) {
            half8 bf = *(const half8*)(Wt + (size_t)(nt * 16 + c16) * D + koff);
            acc[0][nt] = __builtin_amdgcn_mfma_f32_16x16x32_f16(a0, bf, acc[0][nt], 0, 0, 0);
            acc[1][nt] = __builtin_amdgcn_mfma_f32_16x16x32_f16(a1, bf, acc[1][nt], 0, 0, 0);
        }
    }

    // C/D: col = lane&15, row = quad*4 + reg
#pragma unroll
    for (int rt = 0; rt < 2; ++rt) {
        int mt = m0 + rt * 16;
#pragma unroll
        for (int i = 0; i < 4; ++i) {
            int grow = mt + quad * 4 + i;
            if (grow < N) {
                float s = dinv[grow];
                unsigned char* orow = out8 + (size_t)grow * D + c16;
#pragma unroll
                for (int nt = 0; nt < 8; ++nt)
                    orow[nt * 16] = f8enc(acc[rt][nt][i] * s);
            }
        }
    }
}

// ---------------- Phase C fused: parallel rank-scatter + GEMM-1 -------------
__global__ __launch_bounds__(256) void k_fuse(const int* __restrict__ ei,
                                              const unsigned char* __restrict__ hist,
                                              const unsigned char* __restrict__ rank,
                                              unsigned short* __restrict__ csr,
                                              const float* __restrict__ x,
                                              const __half* __restrict__ Wt1,
                                              const float* __restrict__ dinv,
                                              unsigned char* __restrict__ out8) {
    int b = blockIdx.x, m = b % 3;
    if (m < 2) {
        // ---- scatter: fully parallel, slot = pref[chunk][c] + rank[e] ----
        int sb = (b / 3) * 2 + m;
        int t = sb * 256 + threadIdx.x;
        if (t >= T4) return;
#pragma unroll
        for (int i = 0; i < 4; ++i) {
            int e = t + i * T4;
            int c = ei[E + e];
            int r = ei[e];
            int chunk = e / EPB;
            int slot = (int)hist[(size_t)chunk * 50000 + c] + (int)rank[e];
            if (slot < CAP) csr[(c << 6) + slot] = (unsigned short)r;
        }
        return;
    }
    // ---- gemm branch ----
    mfma_gemm<float>(x, Wt1, dinv, out8, (b / 3) * 128, threadIdx.x);
}

// ---------------- GEMM layer 2 (fp16 A -> fp8 out) ----------------
__global__ __launch_bounds__(256) void k_gemm(const __half* __restrict__ A,
                                              const __half* __restrict__ Wt,
                                              const float* __restrict__ dinv,
                                              unsigned char* __restrict__ out8) {
    mfma_gemm<__half>(A, Wt, dinv, out8, blockIdx.x * 128, threadIdx.x);
}

// ---------------- Aggregation core (1 wave/node, fp8 row-sum) --------------
__device__ __forceinline__ float agg_core(int c, int lane,
                                          const unsigned char* __restrict__ hs8,
                                          const int* __restrict__ deg,
                                          const unsigned short* __restrict__ csr,
                                          float* a0) {
    int qw = lane >> 4;         // 0..3: edge within group of 4
    int q  = lane & 15;         // column group: bytes q*8..q*8+7
    int dgRaw = deg[c];
    int dg = dgRaw < CAP ? dgRaw : CAP;
    float dc = rsqrtf((float)(dgRaw + 1));
    int e0 = c << 6;

    float a1[8] = {0, 0, 0, 0, 0, 0, 0, 0};
    float a2[8] = {0, 0, 0, 0, 0, 0, 0, 0};
    float a3[8] = {0, 0, 0, 0, 0, 0, 0, 0};
#pragma unroll
    for (int t = 0; t < 8; ++t) a0[t] = 0.f;
    if (qw == 0)                // self loop (hs8[c] already = dinv[c]*h[c])
        add8f8(a0, *(const uint2*)&hs8[(size_t)c * D + q * 8]);

    int j = 0;
    for (; j + 16 <= dg; j += 16) {
        int r0 = csr[e0 + j + qw];
        int r1 = csr[e0 + j + 4 + qw];
        int r2 = csr[e0 + j + 8 + qw];
        int r3 = csr[e0 + j + 12 + qw];
        uint2 u0 = *(const uint2*)&hs8[(size_t)r0 * D + q * 8];
        uint2 u1 = *(const uint2*)&hs8[(size_t)r1 * D + q * 8];
        uint2 u2 = *(const uint2*)&hs8[(size_t)r2 * D + q * 8];
        uint2 u3 = *(const uint2*)&hs8[(size_t)r3 * D + q * 8];
        add8f8(a0, u0); add8f8(a1, u1); add8f8(a2, u2); add8f8(a3, u3);
    }
    if (j + 8 <= dg) {
        int r0 = csr[e0 + j + qw];
        int r1 = csr[e0 + j + 4 + qw];
        uint2 u0 = *(const uint2*)&hs8[(size_t)r0 * D + q * 8];
        uint2 u1 = *(const uint2*)&hs8[(size_t)r1 * D + q * 8];
        add8f8(a0, u0); add8f8(a1, u1);
        j += 8;
    }
    if (j + 4 <= dg) {
        int r0 = csr[e0 + j + qw];
        add8f8(a0, *(const uint2*)&hs8[(size_t)r0 * D + q * 8]);
        j += 4;
    }
    int rem = dg - j;                     // 0..3
    if (qw < rem) {
        int r0 = csr[e0 + j + qw];
        add8f8(a1, *(const uint2*)&hs8[(size_t)r0 * D + q * 8]);
    }

#pragma unroll
    for (int t = 0; t < 8; ++t) a0[t] += a1[t];
#pragma unroll
    for (int t = 0; t < 8; ++t) a2[t] += a3[t];
#pragma unroll
    for (int t = 0; t < 8; ++t) a0[t] += a2[t];
#pragma unroll
    for (int t = 0; t < 8; ++t) a0[t] += __shfl_xor(a0[t], 16, 64);
#pragma unroll
    for (int t = 0; t < 8; ++t) a0[t] += __shfl_xor(a0[t], 32, 64);
    return dc;
}

// layer-1 agg: writes fp16 rows (coalesced; gemm2 scales its own output)
__global__ __launch_bounds__(256) void k_agg1(const unsigned char* __restrict__ hs8,
                                              const int* __restrict__ deg,
                                              const unsigned short* __restrict__ csr,
                                              const float* __restrict__ bias,
                                              __half* __restrict__ outH) {
    int wave = threadIdx.x >> 6;
    int lane = threadIdx.x & 63;
    int c = blockIdx.x * 4 + wave;
    float a0[8];
    float dc = agg_core(c, lane, hs8, deg, csr, a0);
    if ((lane >> 4) == 0) {
        int q = lane & 15;
        union { __half2 h[4]; uint4 u; } p;
#pragma unroll
        for (int i = 0; i < 4; ++i) {
            float xv = fmaxf(fmaf(dc, a0[2 * i],     bias[q * 8 + 2 * i]),     0.f);
            float yv = fmaxf(fmaf(dc, a0[2 * i + 1], bias[q * 8 + 2 * i + 1]), 0.f);
            p.h[i] = __floats2half2_rn(xv, yv);
        }
        *(uint4*)&outH[(size_t)c * D + q * 8] = p.u;
    }
}

// layer-2 agg: reduces h2 rows straight into per-block pool partials
__global__ __launch_bounds__(256) void k_agg2(const unsigned char* __restrict__ hs8,
                                              const int* __restrict__ deg,
                                              const unsigned short* __restrict__ csr,
                                              const float* __restrict__ bias,
                                              float* __restrict__ gpart) {
    __shared__ float gblk[4][128];
    int wave = threadIdx.x >> 6;
    int lane = threadIdx.x & 63;
    int c = blockIdx.x * 4 + wave;
    float a0[8];
    float dc = agg_core(c, lane, hs8, deg, csr, a0);
    if ((lane >> 4) == 0) {
        int q = lane & 15;
#pragma unroll
        for (int i = 0; i < 8; ++i)
            gblk[wave][q * 8 + i] = fmaxf(fmaf(dc, a0[i], bias[q * 8 + i]), 0.f);
    }
    __syncthreads();
    int t = threadIdx.x;
    if (t < 128)
        gpart[(size_t)blockIdx.x * 128 + t] =
            gblk[0][t] + gblk[1][t] + gblk[2][t] + gblk[3][t];
}

// ---------------- Tail: pool (256 blocks) + last-block classifier ----------
__global__ __launch_bounds__(256) void k_tail(const float* __restrict__ gpart,
                                              float* __restrict__ gpart2,
                                              const float* __restrict__ Wc,
                                              const float* __restrict__ bc,
                                              int* __restrict__ ctr,
                                              float* __restrict__ out) {
    __shared__ float red[256];
    __shared__ float g[128];
    __shared__ int lastf;
    int t = threadIdx.x;
    int d = t & 127, half = t >> 7;
    int b = blockIdx.x;                 // 256 blocks
    int per = (NW + 255) / 256;         // 49
    int r0 = b * per;
    int r1 = r0 + per;
    if (r1 > NW) r1 = NW;
    float acc = 0.f;
    for (int r = r0 + half; r < r1; r += 2)
        acc += gpart[(size_t)r * 128 + d];
    red[t] = acc;
    __syncthreads();
    if (half == 0) gpart2[(size_t)b * 128 + d] = red[d] + red[128 + d];
    __syncthreads();
    if (t == 0) {
        __threadfence();                        // release gpart2 store
        lastf = (atomicAdd(ctr, 1) == 255);
    }
    __syncthreads();
    if (!lastf) return;
    __threadfence();                            // acquire others' stores
    // final: g = sum(gpart2)/N; out = g@Wc + bc
    float s = 0.f;
    for (int w = half * 128; w < half * 128 + 128; ++w)
        s += gpart2[(size_t)w * 128 + d];
    red[t] = s;
    __syncthreads();
    if (half == 0) g[d] = (red[d] + red[128 + d]) * (1.0f / (float)N);
    __syncthreads();
    if (t < DOUT) {
        float a = bc[t];
        for (int dd = 0; dd < 128; ++dd) a = fmaf(g[dd], Wc[dd * DOUT + t], a);
        out[t] = a;
    }
}

extern "C" void kernel_launch(void* const* d_in, const int* in_sizes, int n_in,
                              void* d_out, int out_size, void* d_ws, size_t ws_size,
                              hipStream_t stream) {
    const float* x  = (const float*)d_in[0];
    const int*   ei = (const int*)d_in[1];
    const float* W1 = (const float*)d_in[2];
    const float* b1 = (const float*)d_in[3];
    const float* W2 = (const float*)d_in[4];
    const float* b2 = (const float*)d_in[5];
    const float* Wc = (const float*)d_in[6];
    const float* bc = (const float*)d_in[7];
    float* out = (float*)d_out;

    char* ws = (char*)d_ws;
    size_t off = 0;
    auto alloc = [&](size_t bytes) {
        void* p = ws + off;
        off += (bytes + 511) & ~(size_t)511;
        return p;
    };
    unsigned char*  hist   = (unsigned char*) alloc((size_t)HB * 50000);     // 6.4MB
    unsigned char*  rank   = (unsigned char*) alloc((size_t)E);              // 0.8MB
    int*            deg    = (int*)           alloc((size_t)N * 4);
    float*          dinv   = (float*)         alloc((size_t)N * 4);
    unsigned short* csr    = (unsigned short*)alloc((size_t)N * CAP * 2);    // 6.4MB
    unsigned char*  hs8    = (unsigned char*) alloc((size_t)N * D);          // 6.4MB
    __half*         hactH  = (__half*)        alloc((size_t)N * D * 2);      // 12.8MB
    __half*         Wt1    = (__half*)        alloc((size_t)D * D * 2);      // 32KB
    __half*         Wt2    = (__half*)        alloc((size_t)D * D * 2);      // 32KB
    float*          gpart  = (float*)         alloc((size_t)NW * D * 4);     // 6.4MB
    float*          gpart2 = (float*)         alloc((size_t)256 * D * 4);
    int*            ctr    = (int*)           alloc(512);
    (void)ws_size; (void)in_sizes; (void)n_in; (void)out_size;

    const int* col = ei + E;

    // Phase A: histograms + ranks + W transposes (one dispatch)
    k_hist<<<HB + 32, 1024, 0, stream>>>(col, hist, rank, W1, W2, Wt1, Wt2);
    // Phase B: per-node prefix; deg/dinv; zero ctr
    k_colscan<<<(N + 255) / 256, 256, 0, stream>>>(hist, deg, dinv, ctr);
    // Phase C: parallel scatter (2/3) + MFMA gemm layer 1 (1/3) -> fp8 rows
    k_fuse<<<GF, 256, 0, stream>>>(ei, hist, rank, csr, x, Wt1, dinv, hs8);

    k_agg1<<<NW, 256, 0, stream>>>(hs8, deg, csr, b1, hactH);
    k_gemm<<<GM, 256, 0, stream>>>(hactH, Wt2, dinv, hs8);
    k_agg2<<<NW, 256, 0, stream>>>(hs8, deg, csr, b2, gpart);
    k_tail<<<256, 256, 0, stream>>>(gpart, gpart2, Wc, bc, ctr, out);
}

// Round 14
// 211.996 us; speedup vs baseline: 1.1509x; 1.1509x over previous
//
#include <hip/hip_runtime.h>
#include <hip/hip_fp16.h>

// GCN: h1 = relu(Agg(x@W1)+b1); h2 = relu(Agg(h1@W2)+b2); out = mean(h2)@Wc+bc
// norm(r,c)=dinv[r]*dinv[c] factors: GEMM epilogue prescales rows by dinv[r],
// agg sums rows, scales by dinv[c] at the end.
// R1: agg MLP (88->57). R2-R4: scattered global atomics/fences = fixed-rate
//     memory-side resource — avoid entirely.
// R5: bucket+fusion (339). R6: interleave+fp16 (272). R7: zero-atomic build (254).
// R9: MFMA fp16 gemms. R10: rank-at-count parallel scatter (230).
// R11: deeper agg ILP — NEUTRAL (aggs throughput-bound).
// R12: fp8 e4m3 gather rows (aggs faster) BUT merged pool+final via
//      last-block-done = 50us regression — 256 device-scope threadfences
//      serialize at the coherence point (same lesson as R2-R4).
// R13: revert tail to separate k_pool + k_final (no atomics/fences).

typedef _Float16 half8 __attribute__((ext_vector_type(8)));
typedef float f32x4 __attribute__((ext_vector_type(4)));
typedef float f32x2 __attribute__((ext_vector_type(2)));

constexpr int N = 50000;
constexpr int E = 800000;
constexpr int D = 128;
constexpr int DOUT = 40;
constexpr int CAP = 64;               // slots/node (Poisson(16) tail ~1e-18)
constexpr int HB = 128;               // histogram chunks
constexpr int EPB = E / HB;           // 6250 edges/chunk
constexpr int HWRD = 12500;           // 50000 bytes = 12500 words
constexpr int GM = (N + 127) / 128;   // 391 gemm blocks
constexpr int NW = N / 4;             // 12500 agg blocks
constexpr int T4 = E / 4;             // 200000 scatter threads
constexpr int GF = 3 * GM;            // 1173 = 782 scatter + 391 gemm

// ---------------- Phase A: chunk histograms + per-edge rank + W transpose ---
__global__ __launch_bounds__(1024) void k_hist(const int* __restrict__ col,
                                               unsigned char* __restrict__ hist,
                                               unsigned char* __restrict__ rank,
                                               const float* __restrict__ W1,
                                               const float* __restrict__ W2,
                                               __half* __restrict__ T1,
                                               __half* __restrict__ T2) {
    __shared__ unsigned int h[HWRD];
    int b = blockIdx.x, t = threadIdx.x;
    if (b >= HB) {                        // 32 spare blocks: Wt[n][k]=fp16(W[k][n])
        int o = (b - HB) * 1024 + t;      // 0..32767
        const float* W = (o < 16384) ? W1 : W2;
        __half* T = (o < 16384) ? T1 : T2;
        int oo = o & 16383;
        int n = oo >> 7, k = oo & 127;
        T[oo] = (__half)W[k * 128 + n];
        return;
    }
    for (int i = t; i < HWRD; i += 1024) h[i] = 0;
    __syncthreads();
    int e0 = b * EPB;
    for (int e = e0 + t; e < e0 + EPB; e += 1024) {
        int c = col[e];
        unsigned int old = atomicAdd(&h[c >> 2], 1u << ((c & 3) * 8));
        rank[e] = (unsigned char)((old >> ((c & 3) * 8)) & 0xff);
    }
    __syncthreads();
    unsigned int* out = (unsigned int*)(hist + (size_t)b * 50000);
    for (int i = t; i < HWRD; i += 1024) out[i] = h[i];
}

// ---------------- Phase B: per-node prefix over chunks; deg + dinv ---------
__global__ void k_colscan(unsigned char* __restrict__ hist, int* __restrict__ deg,
                          float* __restrict__ dinv) {
    int c = blockIdx.x * 256 + threadIdx.x;
    if (c >= N) return;
    int sum = 0;
#pragma unroll 4
    for (int b = 0; b < HB; ++b) {
        size_t idx = (size_t)b * 50000 + c;
        int v = hist[idx];
        hist[idx] = (unsigned char)sum;   // exclusive prefix (deg<=255)
        sum += v;
    }
    deg[c] = sum;
    dinv[c] = rsqrtf((float)(sum + 1));   // +1 self loop
}

// ---------------- fp8 helpers (OCP e4m3 on gfx950) ----------------
__device__ __forceinline__ unsigned char f8enc(float v) {
    return (unsigned char)(__builtin_amdgcn_cvt_pk_fp8_f32(v, v, 0, false) & 0xff);
}
__device__ __forceinline__ void add8f8(float* a, uint2 u) {
    f32x2 f0 = __builtin_amdgcn_cvt_pk_f32_fp8(u.x, false);
    f32x2 f1 = __builtin_amdgcn_cvt_pk_f32_fp8(u.x, true);
    f32x2 f2 = __builtin_amdgcn_cvt_pk_f32_fp8(u.y, false);
    f32x2 f3 = __builtin_amdgcn_cvt_pk_f32_fp8(u.y, true);
    a[0] += f0[0]; a[1] += f0[1]; a[2] += f1[0]; a[3] += f1[1];
    a[4] += f2[0]; a[5] += f2[1]; a[6] += f3[0]; a[7] += f3[1];
}

// ---------------- MFMA GEMM: out8[r] = fp8(dinv[r] * (A[r] @ W)) -----------
__device__ __forceinline__ half8 ldA(const float* rowp, int koff) {
    float4 u0 = *(const float4*)(rowp + koff);
    float4 u1 = *(const float4*)(rowp + koff + 4);
    half8 r;
    r[0] = (_Float16)u0.x; r[1] = (_Float16)u0.y;
    r[2] = (_Float16)u0.z; r[3] = (_Float16)u0.w;
    r[4] = (_Float16)u1.x; r[5] = (_Float16)u1.y;
    r[6] = (_Float16)u1.z; r[7] = (_Float16)u1.w;
    return r;
}
__device__ __forceinline__ half8 ldA(const __half* rowp, int koff) {
    return *(const half8*)(rowp + koff);
}

template <typename TA>
__device__ __forceinline__ void mfma_gemm(const TA* __restrict__ A,
                                          const __half* __restrict__ Wt,
                                          const float* __restrict__ dinv,
                                          unsigned char* __restrict__ out8,
                                          int row0, int tid) {
    int wave = tid >> 6, lane = tid & 63;
    int quad = lane >> 4, c16 = lane & 15;
    int m0 = row0 + wave * 32;
    int ra = m0 + c16;      if (ra >= N) ra = 0;   // OOB rows: dummy read row 0
    int rb = m0 + 16 + c16; if (rb >= N) rb = 0;
    const TA* pa = A + (size_t)ra * D;
    const TA* pb = A + (size_t)rb * D;

    f32x4 acc[2][8];
#pragma unroll
    for (int i = 0; i < 2; ++i)
#pragma unroll
        for (int j = 0; j < 8; ++j) acc[i][j] = (f32x4){0.f, 0.f, 0.f, 0.f};

#pragma unroll
    for (int kq = 0; kq < 4; ++kq) {
        int koff = kq * 32 + quad * 8;
        half8 a0 = ldA(pa, koff);
        half8 a1 = ldA(pb, koff);
#pragma unroll
        for (int nt = 0; nt < 8; ++nt) {
            half8 bf = *(const half8*)(Wt + (size_t)(nt * 16 + c16) * D + koff);
            acc[0][nt] = __builtin_amdgcn_mfma_f32_16x16x32_f16(a0, bf, acc[0][nt], 0, 0, 0);
            acc[1][nt] = __builtin_amdgcn_mfma_f32_16x16x32_f16(a1, bf, acc[1][nt], 0, 0, 0);
        }
    }

    // C/D: col = lane&15, row = quad*4 + reg
#pragma unroll
    for (int rt = 0; rt < 2; ++rt) {
        int mt = m0 + rt * 16;
#pragma unroll
        for (int i = 0; i < 4; ++i) {
            int grow = mt + quad * 4 + i;
            if (grow < N) {
                float s = dinv[grow];
                unsigned char* orow = out8 + (size_t)grow * D + c16;
#pragma unroll
                for (int nt = 0; nt < 8; ++nt)
                    orow[nt * 16] = f8enc(acc[rt][nt][i] * s);
            }
        }
    }
}

// ---------------- Phase C fused: parallel rank-scatter + GEMM-1 -------------
__global__ __launch_bounds__(256) void k_fuse(const int* __restrict__ ei,
                                              const unsigned char* __restrict__ hist,
                                              const unsigned char* __restrict__ rank,
                                              unsigned short* __restrict__ csr,
                                              const float* __restrict__ x,
                                              const __half* __restrict__ Wt1,
                                              const float* __restrict__ dinv,
                                              unsigned char* __restrict__ out8) {
    int b = blockIdx.x, m = b % 3;
    if (m < 2) {
        // ---- scatter: fully parallel, slot = pref[chunk][c] + rank[e] ----
        int sb = (b / 3) * 2 + m;
        int t = sb * 256 + threadIdx.x;
        if (t >= T4) return;
#pragma unroll
        for (int i = 0; i < 4; ++i) {
            int e = t + i * T4;
            int c = ei[E + e];
            int r = ei[e];
            int chunk = e / EPB;
            int slot = (int)hist[(size_t)chunk * 50000 + c] + (int)rank[e];
            if (slot < CAP) csr[(c << 6) + slot] = (unsigned short)r;
        }
        return;
    }
    // ---- gemm branch ----
    mfma_gemm<float>(x, Wt1, dinv, out8, (b / 3) * 128, threadIdx.x);
}

// ---------------- GEMM layer 2 (fp16 A -> fp8 out) ----------------
__global__ __launch_bounds__(256) void k_gemm(const __half* __restrict__ A,
                                              const __half* __restrict__ Wt,
                                              const float* __restrict__ dinv,
                                              unsigned char* __restrict__ out8) {
    mfma_gemm<__half>(A, Wt, dinv, out8, blockIdx.x * 128, threadIdx.x);
}

// ---------------- Aggregation core (1 wave/node, fp8 row-sum) --------------
__device__ __forceinline__ float agg_core(int c, int lane,
                                          const unsigned char* __restrict__ hs8,
                                          const int* __restrict__ deg,
                                          const unsigned short* __restrict__ csr,
                                          float* a0) {
    int qw = lane >> 4;         // 0..3: edge within group of 4
    int q  = lane & 15;         // column group: bytes q*8..q*8+7
    int dgRaw = deg[c];
    int dg = dgRaw < CAP ? dgRaw : CAP;
    float dc = rsqrtf((float)(dgRaw + 1));
    int e0 = c << 6;

    float a1[8] = {0, 0, 0, 0, 0, 0, 0, 0};
    float a2[8] = {0, 0, 0, 0, 0, 0, 0, 0};
    float a3[8] = {0, 0, 0, 0, 0, 0, 0, 0};
#pragma unroll
    for (int t = 0; t < 8; ++t) a0[t] = 0.f;
    if (qw == 0)                // self loop (hs8[c] already = dinv[c]*h[c])
        add8f8(a0, *(const uint2*)&hs8[(size_t)c * D + q * 8]);

    int j = 0;
    for (; j + 16 <= dg; j += 16) {
        int r0 = csr[e0 + j + qw];
        int r1 = csr[e0 + j + 4 + qw];
        int r2 = csr[e0 + j + 8 + qw];
        int r3 = csr[e0 + j + 12 + qw];
        uint2 u0 = *(const uint2*)&hs8[(size_t)r0 * D + q * 8];
        uint2 u1 = *(const uint2*)&hs8[(size_t)r1 * D + q * 8];
        uint2 u2 = *(const uint2*)&hs8[(size_t)r2 * D + q * 8];
        uint2 u3 = *(const uint2*)&hs8[(size_t)r3 * D + q * 8];
        add8f8(a0, u0); add8f8(a1, u1); add8f8(a2, u2); add8f8(a3, u3);
    }
    if (j + 8 <= dg) {
        int r0 = csr[e0 + j + qw];
        int r1 = csr[e0 + j + 4 + qw];
        uint2 u0 = *(const uint2*)&hs8[(size_t)r0 * D + q * 8];
        uint2 u1 = *(const uint2*)&hs8[(size_t)r1 * D + q * 8];
        add8f8(a0, u0); add8f8(a1, u1);
        j += 8;
    }
    if (j + 4 <= dg) {
        int r0 = csr[e0 + j + qw];
        add8f8(a0, *(const uint2*)&hs8[(size_t)r0 * D + q * 8]);
        j += 4;
    }
    int rem = dg - j;                     // 0..3
    if (qw < rem) {
        int r0 = csr[e0 + j + qw];
        add8f8(a1, *(const uint2*)&hs8[(size_t)r0 * D + q * 8]);
    }

#pragma unroll
    for (int t = 0; t < 8; ++t) a0[t] += a1[t];
#pragma unroll
    for (int t = 0; t < 8; ++t) a2[t] += a3[t];
#pragma unroll
    for (int t = 0; t < 8; ++t) a0[t] += a2[t];
#pragma unroll
    for (int t = 0; t < 8; ++t) a0[t] += __shfl_xor(a0[t], 16, 64);
#pragma unroll
    for (int t = 0; t < 8; ++t) a0[t] += __shfl_xor(a0[t], 32, 64);
    return dc;
}

// layer-1 agg: writes fp16 rows (coalesced; gemm2 scales its own output)
__global__ __launch_bounds__(256) void k_agg1(const unsigned char* __restrict__ hs8,
                                              const int* __restrict__ deg,
                                              const unsigned short* __restrict__ csr,
                                              const float* __restrict__ bias,
                                              __half* __restrict__ outH) {
    int wave = threadIdx.x >> 6;
    int lane = threadIdx.x & 63;
    int c = blockIdx.x * 4 + wave;
    float a0[8];
    float dc = agg_core(c, lane, hs8, deg, csr, a0);
    if ((lane >> 4) == 0) {
        int q = lane & 15;
        union { __half2 h[4]; uint4 u; } p;
#pragma unroll
        for (int i = 0; i < 4; ++i) {
            float xv = fmaxf(fmaf(dc, a0[2 * i],     bias[q * 8 + 2 * i]),     0.f);
            float yv = fmaxf(fmaf(dc, a0[2 * i + 1], bias[q * 8 + 2 * i + 1]), 0.f);
            p.h[i] = __floats2half2_rn(xv, yv);
        }
        *(uint4*)&outH[(size_t)c * D + q * 8] = p.u;
    }
}

// layer-2 agg: reduces h2 rows straight into per-block pool partials
__global__ __launch_bounds__(256) void k_agg2(const unsigned char* __restrict__ hs8,
                                              const int* __restrict__ deg,
                                              const unsigned short* __restrict__ csr,
                                              const float* __restrict__ bias,
                                              float* __restrict__ gpart) {
    __shared__ float gblk[4][128];
    int wave = threadIdx.x >> 6;
    int lane = threadIdx.x & 63;
    int c = blockIdx.x * 4 + wave;
    float a0[8];
    float dc = agg_core(c, lane, hs8, deg, csr, a0);
    if ((lane >> 4) == 0) {
        int q = lane & 15;
#pragma unroll
        for (int i = 0; i < 8; ++i)
            gblk[wave][q * 8 + i] = fmaxf(fmaf(dc, a0[i], bias[q * 8 + i]), 0.f);
    }
    __syncthreads();
    int t = threadIdx.x;
    if (t < 128)
        gpart[(size_t)blockIdx.x * 128 + t] =
            gblk[0][t] + gblk[1][t] + gblk[2][t] + gblk[3][t];
}

// ---------------- Pool stage 2: 12500 partials -> 256 partials --------------
__global__ __launch_bounds__(256) void k_pool(const float* __restrict__ gpart,
                                              float* __restrict__ gpart2) {
    int d = threadIdx.x & 127;
    int half = threadIdx.x >> 7;
    int b = blockIdx.x;                 // 256 blocks
    int per = (NW + 255) / 256;         // 49
    int r0 = b * per;
    int r1 = r0 + per;
    if (r1 > NW) r1 = NW;
    float acc = 0.f;
    for (int r = r0 + half; r < r1; r += 2)
        acc += gpart[(size_t)r * D + d];
    __shared__ float red[256];
    red[threadIdx.x] = acc;
    __syncthreads();
    if (half == 0) gpart2[(size_t)b * D + d] = red[d] + red[128 + d];
}

// ---------------- Final: g = sum(gpart2)/N; out = g@Wc + bc ----------------
__global__ __launch_bounds__(512) void k_final(const float* __restrict__ gpart2,
                                               const float* __restrict__ Wc,
                                               const float* __restrict__ bc,
                                               float* __restrict__ out) {
    __shared__ float g[D];
    __shared__ float red[512];
    int t = threadIdx.x;
    int d = t & 127, grp = t >> 7;
    float s = 0.f;
#pragma unroll 4
    for (int w = grp * 64; w < grp * 64 + 64; ++w)
        s += gpart2[(size_t)w * D + d];
    red[t] = s;
    __syncthreads();
    if (grp == 0)
        g[d] = (red[d] + red[128 + d] + red[256 + d] + red[384 + d]) * (1.0f / (float)N);
    __syncthreads();
    if (t < DOUT) {
        float acc = bc[t];
        for (int dd = 0; dd < D; ++dd) acc = fmaf(g[dd], Wc[dd * DOUT + t], acc);
        out[t] = acc;
    }
}

extern "C" void kernel_launch(void* const* d_in, const int* in_sizes, int n_in,
                              void* d_out, int out_size, void* d_ws, size_t ws_size,
                              hipStream_t stream) {
    const float* x  = (const float*)d_in[0];
    const int*   ei = (const int*)d_in[1];
    const float* W1 = (const float*)d_in[2];
    const float* b1 = (const float*)d_in[3];
    const float* W2 = (const float*)d_in[4];
    const float* b2 = (const float*)d_in[5];
    const float* Wc = (const float*)d_in[6];
    const float* bc = (const float*)d_in[7];
    float* out = (float*)d_out;

    char* ws = (char*)d_ws;
    size_t off = 0;
    auto alloc = [&](size_t bytes) {
        void* p = ws + off;
        off += (bytes + 511) & ~(size_t)511;
        return p;
    };
    unsigned char*  hist   = (unsigned char*) alloc((size_t)HB * 50000);     // 6.4MB
    unsigned char*  rank   = (unsigned char*) alloc((size_t)E);              // 0.8MB
    int*            deg    = (int*)           alloc((size_t)N * 4);
    float*          dinv   = (float*)         alloc((size_t)N * 4);
    unsigned short* csr    = (unsigned short*)alloc((size_t)N * CAP * 2);    // 6.4MB
    unsigned char*  hs8    = (unsigned char*) alloc((size_t)N * D);          // 6.4MB
    __half*         hactH  = (__half*)        alloc((size_t)N * D * 2);      // 12.8MB
    __half*         Wt1    = (__half*)        alloc((size_t)D * D * 2);      // 32KB
    __half*         Wt2    = (__half*)        alloc((size_t)D * D * 2);      // 32KB
    float*          gpart  = (float*)         alloc((size_t)NW * D * 4);     // 6.4MB
    float*          gpart2 = (float*)         alloc((size_t)256 * D * 4);
    (void)ws_size; (void)in_sizes; (void)n_in; (void)out_size;

    const int* col = ei + E;

    // Phase A: histograms + ranks + W transposes (one dispatch)
    k_hist<<<HB + 32, 1024, 0, stream>>>(col, hist, rank, W1, W2, Wt1, Wt2);
    // Phase B: per-node prefix; deg/dinv
    k_colscan<<<(N + 255) / 256, 256, 0, stream>>>(hist, deg, dinv);
    // Phase C: parallel scatter (2/3) + MFMA gemm layer 1 (1/3) -> fp8 rows
    k_fuse<<<GF, 256, 0, stream>>>(ei, hist, rank, csr, x, Wt1, dinv, hs8);

    k_agg1<<<NW, 256, 0, stream>>>(hs8, deg, csr, b1, hactH);
    k_gemm<<<GM, 256, 0, stream>>>(hactH, Wt2, dinv, hs8);
    k_agg2<<<NW, 256, 0, stream>>>(hs8, deg, csr, b2, gpart);
    k_pool<<<256, 256, 0, stream>>>(gpart, gpart2);
    k_final<<<1, 512, 0, stream>>>(gpart2, Wc, bc, out);
}